// Round 3
// baseline (278.708 us; speedup 1.0000x reference)
//
#include <hip/hip_runtime.h>
#include <hip/hip_bf16.h>
#include <math.h>

// Problem constants (from reference setup): b=4, c=128, h=16, w=16
//   D    = 128*16*16 = 32768 floats per (n,b) slice
//   DIM4 = D/4 = 8192 float4 per slice
#define BQ    4
#define DIM   32768
#define DIM4  8192
#define ITEM4 32768   // (4*32768)/4 float4 per memory item
#define EPS   1e-8f
#define QREG  16      // float4 per thread of register-resident query slice
#define WPB   8       // waves per block in dot kernel (512 threads)

// ---------------- Kernel A: query norm^2 per batch row ----------------
__global__ void qnorm_kernel(const float* __restrict__ q, float* __restrict__ qn2) {
    const int b = blockIdx.x;
    const float4* q4 = (const float4*)(q + (size_t)b * DIM);
    float nrm = 0.f;
    for (int i = threadIdx.x; i < DIM4; i += blockDim.x) {
        float4 v = q4[i];
        nrm += v.x * v.x + v.y * v.y + v.z * v.z + v.w * v.w;
    }
    for (int off = 32; off > 0; off >>= 1) nrm += __shfl_down(nrm, off);
    __shared__ float s[16];
    const int wid = threadIdx.x >> 6;
    if ((threadIdx.x & 63) == 0) s[wid] = nrm;
    __syncthreads();
    if (threadIdx.x == 0) {
        float tot = 0.f;
        for (int w = 0; w < (int)(blockDim.x >> 6); ++w) tot += s[w];
        qn2[b] = tot;
    }
}

// ---------------- Kernel B: per-(n,b) partial dot(q,m) and ||m||^2 ----------------
// Barrier-free streaming: each block pinned to one batch row b, query slice in
// registers. Per n, each wave reduces its own 16 KB chunk via shuffles and
// writes ONE float2 partial to ws — no LDS, no __syncthreads, so the memory
// pipe never drains between items. Partials (8000 pairs x 8 waves = 512 KB)
// are summed in the top-k kernel's prologue.
__global__ __launch_bounds__(512) void dot_norm_kernel(
        const float* __restrict__ q, const float* __restrict__ mem,
        float2* __restrict__ part, int N) {
    const int b    = blockIdx.x & 3;
    const int bn   = blockIdx.x >> 2;       // block index within this b
    const int nblk = gridDim.x >> 2;        // blocks per b
    const int wid  = threadIdx.x >> 6;
    const int lane = threadIdx.x & 63;

    const float4* q4 = (const float4*)(q + (size_t)b * DIM);
    float4 qr[QREG];
    #pragma unroll
    for (int j = 0; j < QREG; ++j) qr[j] = q4[threadIdx.x + j * 512];

    for (int n = bn; n < N; n += nblk) {
        const float4* m4 = (const float4*)(mem + ((size_t)n * BQ + b) * DIM);
        float dot = 0.f, nrm = 0.f;
        #pragma unroll
        for (int j = 0; j < QREG; ++j) {
            float4 m = m4[threadIdx.x + j * 512];
            float4 a = qr[j];
            dot += a.x * m.x + a.y * m.y + a.z * m.z + a.w * m.w;
            nrm += m.x * m.x + m.y * m.y + m.z * m.z + m.w * m.w;
        }
        #pragma unroll
        for (int off = 32; off > 0; off >>= 1) {
            dot += __shfl_down(dot, off);
            nrm += __shfl_down(nrm, off);
        }
        if (lane == 0)
            part[((size_t)n * BQ + b) * WPB + wid] = make_float2(dot, nrm);
    }
}

// ---------------- Kernel C: partial-sum -> sims -> top-k -> softmax ----------------
__global__ __launch_bounds__(512) void topk_softmax_kernel(
        const float* __restrict__ qn2,
        const float2* __restrict__ part,
        const int* __restrict__ kp,
        float* __restrict__ weights,
        int* __restrict__ topidx,
        int N) {
    const int k = *kp;
    __shared__ float sims[2048];
    __shared__ float swv[8];
    __shared__ int   swi[8];
    __shared__ float qden[BQ];
    __shared__ float tvals[64];
    __shared__ int   tidxs[64];

    if (threadIdx.x < BQ) qden[threadIdx.x] = fmaxf(sqrtf(qn2[threadIdx.x]), EPS);
    __syncthreads();

    // Sum the 8 wave-partials per (n,b), build sims[n].
    for (int n = threadIdx.x; n < N; n += blockDim.x) {
        const float4* p4 = (const float4*)(part + (size_t)n * BQ * WPB);
        float s = 0.f;
        #pragma unroll
        for (int b = 0; b < BQ; ++b) {
            float d = 0.f, m2 = 0.f;
            #pragma unroll
            for (int j = 0; j < WPB / 2; ++j) {
                float4 v = p4[b * (WPB / 2) + j];   // (dot,nrm,dot,nrm)
                d  += v.x + v.z;
                m2 += v.y + v.w;
            }
            s += d / (qden[b] * fmaxf(sqrtf(m2), EPS));
        }
        sims[n] = s * (1.0f / BQ);
    }
    __syncthreads();

    const int lane = threadIdx.x & 63;
    const int wid  = threadIdx.x >> 6;

    for (int it = 0; it < k; ++it) {
        float best = -INFINITY;
        int bidx = 0x7fffffff;
        for (int n = threadIdx.x; n < N; n += blockDim.x) {
            float v = sims[n];
            if (v > best || (v == best && n < bidx)) { best = v; bidx = n; }
        }
        // wave-level argmax (lowest-index tie-break), no barriers
        #pragma unroll
        for (int off = 32; off > 0; off >>= 1) {
            float ov = __shfl_down(best, off);
            int   oi = __shfl_down(bidx, off);
            if (ov > best || (ov == best && oi < bidx)) { best = ov; bidx = oi; }
        }
        if (lane == 0) { swv[wid] = best; swi[wid] = bidx; }
        __syncthreads();
        if (threadIdx.x == 0) {
            float bv = swv[0]; int bi = swi[0];
            #pragma unroll
            for (int w = 1; w < 8; ++w) {
                if (swv[w] > bv || (swv[w] == bv && swi[w] < bi)) { bv = swv[w]; bi = swi[w]; }
            }
            tvals[it] = bv;
            tidxs[it] = bi;
            sims[bi]  = -INFINITY;   // exclude for next round
        }
        __syncthreads();
    }

    if (threadIdx.x == 0) {
        float m = tvals[0];          // descending: first is the max
        float sum = 0.f;
        for (int i = 0; i < k; ++i) sum += expf(tvals[i] - m);
        float inv = 1.0f / sum;
        for (int i = 0; i < k; ++i) {
            weights[i] = expf(tvals[i] - m) * inv;
            topidx[i]  = tidxs[i];
        }
    }
}

// ---------------- Kernel D: weighted gather-sum of selected items ----------------
__global__ void wsum_kernel(const float* __restrict__ mem,
                            const float* __restrict__ weights,
                            const int* __restrict__ topidx,
                            const int* __restrict__ kp,
                            float* __restrict__ out) {
    const int k = *kp;
    __shared__ float w[64];
    __shared__ int   id[64];
    if ((int)threadIdx.x < k) {
        w[threadIdx.x]  = weights[threadIdx.x];
        id[threadIdx.x] = topidx[threadIdx.x];
    }
    __syncthreads();
    const int t = blockIdx.x * blockDim.x + threadIdx.x;   // float4 index within item
    if (t >= ITEM4) return;
    const float4* m4 = (const float4*)mem;
    float4 acc = {0.f, 0.f, 0.f, 0.f};
    for (int j = 0; j < k; ++j) {
        float4 v = m4[(size_t)id[j] * ITEM4 + t];
        float wj = w[j];
        acc.x += wj * v.x; acc.y += wj * v.y; acc.z += wj * v.z; acc.w += wj * v.w;
    }
    ((float4*)out)[t] = acc;
}

extern "C" void kernel_launch(void* const* d_in, const int* in_sizes, int n_in,
                              void* d_out, int out_size, void* d_ws, size_t ws_size,
                              hipStream_t stream) {
    const float* q   = (const float*)d_in[0];   // [4,128,16,16]
    const float* mem = (const float*)d_in[1];   // [N,4,128,16,16]
    const int*   kp  = (const int*)d_in[2];     // scalar k
    float* out = (float*)d_out;

    const int N = in_sizes[1] / (BQ * DIM);     // 2000

    // Workspace layout (floats):
    float*  qn2  = (float*)d_ws;                 // 4 (padded to 8 -> 32 B, float4-aligned)
    float2* part = (float2*)(qn2 + 8);           // N*BQ*WPB float2 = 512 KB
    float*  wts  = (float*)(part + (size_t)N * BQ * WPB);  // 64
    int*    tidx = (int*)(wts + 64);             // 64

    qnorm_kernel<<<BQ, 256, 0, stream>>>(q, qn2);
    dot_norm_kernel<<<1024, 512, 0, stream>>>(q, mem, part, N);
    topk_softmax_kernel<<<1, 512, 0, stream>>>(qn2, part, kp, wts, tidx, N);
    wsum_kernel<<<512, 64, 0, stream>>>(mem, wts, tidx, kp, out);
}

// Round 5
// 255.677 us; speedup vs baseline: 1.0901x; 1.0901x over previous
//
#include <hip/hip_runtime.h>
#include <hip/hip_bf16.h>
#include <math.h>

// Problem constants (from reference setup): b=4, c=128, h=16, w=16
//   D    = 128*16*16 = 32768 floats per (n,b) slice
//   DIM4 = D/4 = 8192 float4 per slice; 128 KB per slice
#define BQ    4
#define DIM   32768
#define DIM4  8192
#define ITEM4 32768   // (4*32768)/4 float4 per memory item
#define EPS   1e-8f

// ---------------- Kernel B: one WAVE per (n,b) slice ----------------
// Each wave streams one contiguous 128 KB memory slice (128 float4/lane),
// re-reads the matching 128 KB query slice from L2 (q is 512 KB total,
// L2-resident & replicated per XCD), shuffle-reduces dot and |m|^2 in-wave,
// and writes a single float2. No LDS, no barriers, no cross-wave coupling:
// every wave's HBM stream is sequential.
__global__ __launch_bounds__(256) void dot_norm_kernel(
        const float* __restrict__ q, const float* __restrict__ mem,
        float2* __restrict__ dn, int NP) {
    const int lane = threadIdx.x & 63;
    const int gw   = (blockIdx.x * blockDim.x + threadIdx.x) >> 6;  // global wave id
    const int NW   = (gridDim.x * blockDim.x) >> 6;

    for (int pair = gw; pair < NP; pair += NW) {
        const int b = pair & 3;
        const float4* m4 = (const float4*)(mem + (size_t)pair * DIM);
        const float4* q4 = (const float4*)(q + (size_t)b * DIM);
        float dot = 0.f, nrm = 0.f;
        #pragma unroll 8
        for (int j = 0; j < DIM4 / 64; ++j) {   // 128 float4 per lane
            float4 m = m4[lane + j * 64];
            float4 a = q4[lane + j * 64];
            dot += a.x * m.x + a.y * m.y + a.z * m.z + a.w * m.w;
            nrm += m.x * m.x + m.y * m.y + m.z * m.z + m.w * m.w;
        }
        #pragma unroll
        for (int off = 32; off > 0; off >>= 1) {
            dot += __shfl_down(dot, off);
            nrm += __shfl_down(nrm, off);
        }
        if (lane == 0) dn[pair] = make_float2(dot, nrm);
    }
}

// ---------------- Kernel C: qnorm + sims -> top-k -> softmax ----------------
__global__ __launch_bounds__(512) void topk_softmax_kernel(
        const float* __restrict__ q,
        const float2* __restrict__ dn,
        const int* __restrict__ kp,
        float* __restrict__ weights,
        int* __restrict__ topidx,
        int N) {
    const int k    = *kp;
    const int lane = threadIdx.x & 63;
    const int wid  = threadIdx.x >> 6;

    __shared__ float sims[2048];
    __shared__ float sq[8];
    __shared__ float qden[BQ];
    __shared__ float swv[8];
    __shared__ int   swi[8];
    __shared__ float tvals[64];
    __shared__ int   tidxs[64];

    // --- query norms: wave w handles (b = w&3, half = w>>2), 64 float4/lane ---
    {
        const int b = wid & 3, half = wid >> 2;
        const float4* q4 = (const float4*)(q + (size_t)b * DIM) + half * (DIM4 / 2);
        float s = 0.f;
        #pragma unroll 8
        for (int j = 0; j < 64; ++j) {          // 64 lanes x 64 = 4096 float4 = half slice
            float4 v = q4[lane + j * 64];
            s += v.x * v.x + v.y * v.y + v.z * v.z + v.w * v.w;
        }
        #pragma unroll
        for (int off = 32; off > 0; off >>= 1) s += __shfl_down(s, off);
        if (lane == 0) sq[wid] = s;
    }
    __syncthreads();
    if (threadIdx.x < BQ)
        qden[threadIdx.x] = fmaxf(sqrtf(sq[threadIdx.x] + sq[threadIdx.x + 4]), EPS);
    __syncthreads();

    // --- sims[n] from per-pair (dot, |m|^2) ---
    for (int n = threadIdx.x; n < N; n += blockDim.x) {
        const float4* p4 = (const float4*)(dn + (size_t)n * BQ);  // 2x float4 = 4x float2
        float4 v0 = p4[0];  // (dot0, nrm0, dot1, nrm1)
        float4 v1 = p4[1];  // (dot2, nrm2, dot3, nrm3)
        float s = v0.x / (qden[0] * fmaxf(sqrtf(v0.y), EPS))
                + v0.z / (qden[1] * fmaxf(sqrtf(v0.w), EPS))
                + v1.x / (qden[2] * fmaxf(sqrtf(v1.y), EPS))
                + v1.z / (qden[3] * fmaxf(sqrtf(v1.w), EPS));
        sims[n] = s * (1.0f / BQ);
    }
    __syncthreads();

    // --- iterative top-k (lowest-index tie-break, matches jax.lax.top_k) ---
    for (int it = 0; it < k; ++it) {
        float best = -INFINITY;
        int bidx = 0x7fffffff;
        for (int n = threadIdx.x; n < N; n += blockDim.x) {
            float v = sims[n];
            if (v > best || (v == best && n < bidx)) { best = v; bidx = n; }
        }
        #pragma unroll
        for (int off = 32; off > 0; off >>= 1) {
            float ov = __shfl_down(best, off);
            int   oi = __shfl_down(bidx, off);
            if (ov > best || (ov == best && oi < bidx)) { best = ov; bidx = oi; }
        }
        if (lane == 0) { swv[wid] = best; swi[wid] = bidx; }
        __syncthreads();
        if (threadIdx.x == 0) {
            float bv = swv[0]; int bi = swi[0];
            #pragma unroll
            for (int w = 1; w < 8; ++w) {
                if (swv[w] > bv || (swv[w] == bv && swi[w] < bi)) { bv = swv[w]; bi = swi[w]; }
            }
            tvals[it] = bv;
            tidxs[it] = bi;
            sims[bi]  = -INFINITY;   // exclude for next round
        }
        __syncthreads();
    }

    if (threadIdx.x == 0) {
        float m = tvals[0];          // descending: first is the max
        float sum = 0.f;
        for (int i = 0; i < k; ++i) sum += expf(tvals[i] - m);
        float inv = 1.0f / sum;
        for (int i = 0; i < k; ++i) {
            weights[i] = expf(tvals[i] - m) * inv;
            topidx[i]  = tidxs[i];
        }
    }
}

// ---------------- Kernel D: weighted gather-sum of selected items ----------------
__global__ __launch_bounds__(128) void wsum_kernel(
        const float* __restrict__ mem,
        const float* __restrict__ weights,
        const int* __restrict__ topidx,
        const int* __restrict__ kp,
        float* __restrict__ out) {
    const int k = *kp;
    __shared__ float w[64];
    __shared__ int   id[64];
    if ((int)threadIdx.x < k) {
        w[threadIdx.x]  = weights[threadIdx.x];
        id[threadIdx.x] = topidx[threadIdx.x];
    }
    __syncthreads();
    const int t = blockIdx.x * blockDim.x + threadIdx.x;   // float4 index within item
    if (t >= ITEM4) return;
    const float4* m4 = (const float4*)mem;
    float4 acc = {0.f, 0.f, 0.f, 0.f};
    for (int j = 0; j < k; ++j) {
        float4 v = m4[(size_t)id[j] * ITEM4 + t];
        float wj = w[j];
        acc.x += wj * v.x; acc.y += wj * v.y; acc.z += wj * v.z; acc.w += wj * v.w;
    }
    ((float4*)out)[t] = acc;
}

extern "C" void kernel_launch(void* const* d_in, const int* in_sizes, int n_in,
                              void* d_out, int out_size, void* d_ws, size_t ws_size,
                              hipStream_t stream) {
    const float* q   = (const float*)d_in[0];   // [4,128,16,16]
    const float* mem = (const float*)d_in[1];   // [N,4,128,16,16]
    const int*   kp  = (const int*)d_in[2];     // scalar k
    float* out = (float*)d_out;

    const int N  = in_sizes[1] / (BQ * DIM);    // 2000
    const int NP = N * BQ;                      // 8000 (n,b) pairs

    // Workspace layout:
    float2* dn   = (float2*)d_ws;               // NP float2 = 64 KB
    float*  wts  = (float*)(dn + NP);           // 64
    int*    tidx = (int*)(wts + 64);            // 64

    // One wave per pair: 8000 waves = 2000 blocks x 4 waves.
    dot_norm_kernel<<<(NP + 3) / 4, 256, 0, stream>>>(q, mem, dn, NP);
    topk_softmax_kernel<<<1, 512, 0, stream>>>(q, dn, kp, wts, tidx, N);
    wsum_kernel<<<(ITEM4 + 127) / 128, 128, 0, stream>>>(mem, wts, tidx, kp, out);
}

// Round 6
// 217.205 us; speedup vs baseline: 1.2832x; 1.1771x over previous
//
#include <hip/hip_runtime.h>
#include <hip/hip_bf16.h>
#include <math.h>

// Problem constants (from reference setup): b=4, c=128, h=16, w=16
//   D    = 128*16*16 = 32768 floats per (n,b) slice
//   DIM4 = D/4 = 8192 float4 per slice; 128 KB per slice
#define BQ    4
#define DIM   32768
#define DIM4  8192
#define ITEM4 32768   // (4*32768)/4 float4 per memory item
#define EPS   1e-8f
#define QREG  16      // float4 per thread of register-resident query slice

// ---------------- Kernel B: block-per-(n,b), full-item load window ----------------
// R2-proven structure: each 512-thread block pins one batch row b (query slice
// in registers) and grid-strides over n. Per item, all 16 float4/thread load
// instructions issue back-to-back -> the whole 128 KB item is one dense burst.
// LDS reduce is double-buffered so each item costs ONE __syncthreads.
__global__ __launch_bounds__(512) void dot_norm_kernel(
        const float* __restrict__ q, const float* __restrict__ mem,
        float2* __restrict__ dn, int N) {
    const int b    = blockIdx.x & 3;
    const int bn   = blockIdx.x >> 2;       // block index within this b
    const int nblk = gridDim.x >> 2;        // blocks per b
    const int wid  = threadIdx.x >> 6;
    const int lane = threadIdx.x & 63;

    const float4* q4 = (const float4*)(q + (size_t)b * DIM);
    float4 qr[QREG];
    #pragma unroll
    for (int j = 0; j < QREG; ++j) qr[j] = q4[threadIdx.x + j * 512];

    __shared__ float sd[2][8], sn[2][8];
    int buf = 0;

    for (int n = bn; n < N; n += nblk, buf ^= 1) {
        const float4* m4 = (const float4*)(mem + ((size_t)n * BQ + b) * DIM);
        float dot = 0.f, nrm = 0.f;
        #pragma unroll
        for (int j = 0; j < QREG; ++j) {
            float4 m = m4[threadIdx.x + j * 512];
            float4 a = qr[j];
            dot += a.x * m.x + a.y * m.y + a.z * m.z + a.w * m.w;
            nrm += m.x * m.x + m.y * m.y + m.z * m.z + m.w * m.w;
        }
        #pragma unroll
        for (int off = 32; off > 0; off >>= 1) {
            dot += __shfl_down(dot, off);
            nrm += __shfl_down(nrm, off);
        }
        if (lane == 0) { sd[buf][wid] = dot; sn[buf][wid] = nrm; }
        __syncthreads();
        if (threadIdx.x == 0) {
            float d = 0.f, n2 = 0.f;
            #pragma unroll
            for (int w = 0; w < 8; ++w) { d += sd[buf][w]; n2 += sn[buf][w]; }
            dn[n * BQ + b] = make_float2(d, n2);
        }
        // No trailing barrier: next iteration uses buf^1; by the time buf is
        // overwritten again (two iterations on), every thread has passed the
        // intervening barrier after t0's read.
    }
}

// ---------------- Kernel C: qnorm + sims -> top-k -> softmax ----------------
// Single block, 512 threads. sims live in registers (4 candidates/thread);
// each of the k rounds is 3 local compares + wave shuffle argmax + 2 barriers.
__global__ __launch_bounds__(512) void topk_softmax_kernel(
        const float* __restrict__ q,
        const float2* __restrict__ dn,
        const int* __restrict__ kp,
        float* __restrict__ weights,
        int* __restrict__ topidx,
        int N) {
    const int k    = *kp;
    const int lane = threadIdx.x & 63;
    const int wid  = threadIdx.x >> 6;

    __shared__ float sq[8];
    __shared__ float qden[BQ];
    __shared__ float swv[8];
    __shared__ int   swi[8];
    __shared__ int   sbi;
    __shared__ float tvals[64];
    __shared__ int   tidxs[64];

    // --- query norms: wave w handles (b = w&3, half = w>>2), 64 float4/lane ---
    {
        const int b = wid & 3, half = wid >> 2;
        const float4* q4 = (const float4*)(q + (size_t)b * DIM) + half * (DIM4 / 2);
        float s = 0.f;
        #pragma unroll 8
        for (int j = 0; j < 64; ++j) {
            float4 v = q4[lane + j * 64];
            s += v.x * v.x + v.y * v.y + v.z * v.z + v.w * v.w;
        }
        #pragma unroll
        for (int off = 32; off > 0; off >>= 1) s += __shfl_down(s, off);
        if (lane == 0) sq[wid] = s;
    }
    __syncthreads();
    if (threadIdx.x < BQ)
        qden[threadIdx.x] = fmaxf(sqrtf(sq[threadIdx.x] + sq[threadIdx.x + 4]), EPS);
    __syncthreads();

    // --- sims in registers: thread t owns n = t, t+512, t+1024, t+1536 ---
    float sv[4];
    #pragma unroll
    for (int i = 0; i < 4; ++i) {
        const int n = threadIdx.x + i * 512;
        if (n < N) {
            const float4* p4 = (const float4*)(dn + (size_t)n * BQ);
            float4 v0 = p4[0];  // (dot0, nrm0, dot1, nrm1)
            float4 v1 = p4[1];  // (dot2, nrm2, dot3, nrm3)
            float s = v0.x / (qden[0] * fmaxf(sqrtf(v0.y), EPS))
                    + v0.z / (qden[1] * fmaxf(sqrtf(v0.w), EPS))
                    + v1.x / (qden[2] * fmaxf(sqrtf(v1.y), EPS))
                    + v1.z / (qden[3] * fmaxf(sqrtf(v1.w), EPS));
            sv[i] = s * (1.0f / BQ);
        } else {
            sv[i] = -INFINITY;
        }
    }

    // --- iterative top-k (lowest-index tie-break, matches jax.lax.top_k) ---
    for (int it = 0; it < k; ++it) {
        // local argmax over 4 regs (ascending i => lowest n wins ties)
        float best = sv[0];
        int bi = threadIdx.x;
        #pragma unroll
        for (int i = 1; i < 4; ++i) {
            if (sv[i] > best) { best = sv[i]; bi = threadIdx.x + i * 512; }
        }
        // wave argmax
        #pragma unroll
        for (int off = 32; off > 0; off >>= 1) {
            float ov = __shfl_down(best, off);
            int   oi = __shfl_down(bi, off);
            if (ov > best || (ov == best && oi < bi)) { best = ov; bi = oi; }
        }
        if (lane == 0) { swv[wid] = best; swi[wid] = bi; }
        __syncthreads();
        if (threadIdx.x == 0) {
            float bv = swv[0]; int bx = swi[0];
            #pragma unroll
            for (int w = 1; w < 8; ++w) {
                if (swv[w] > bv || (swv[w] == bv && swi[w] < bx)) { bv = swv[w]; bx = swi[w]; }
            }
            tvals[it] = bv;
            tidxs[it] = bx;
            sbi = bx;
        }
        __syncthreads();
        // owner invalidates its register copy
        const int won = sbi;
        if ((won & 511) == (int)threadIdx.x) sv[won >> 9] = -INFINITY;
    }

    if (threadIdx.x == 0) {
        float m = tvals[0];          // descending: first is the max
        float sum = 0.f;
        for (int i = 0; i < k; ++i) sum += expf(tvals[i] - m);
        float inv = 1.0f / sum;
        for (int i = 0; i < k; ++i) {
            weights[i] = expf(tvals[i] - m) * inv;
            topidx[i]  = tidxs[i];
        }
    }
}

// ---------------- Kernel D: weighted gather-sum of selected items ----------------
__global__ __launch_bounds__(256) void wsum_kernel(
        const float* __restrict__ mem,
        const float* __restrict__ weights,
        const int* __restrict__ topidx,
        const int* __restrict__ kp,
        float* __restrict__ out) {
    const int k = *kp;
    __shared__ float w[64];
    __shared__ int   id[64];
    if ((int)threadIdx.x < k) {
        w[threadIdx.x]  = weights[threadIdx.x];
        id[threadIdx.x] = topidx[threadIdx.x];
    }
    __syncthreads();
    const int t = blockIdx.x * blockDim.x + threadIdx.x;   // float4 index within item
    if (t >= ITEM4) return;
    const float4* m4 = (const float4*)mem;
    float4 acc = {0.f, 0.f, 0.f, 0.f};
    for (int j = 0; j < k; ++j) {
        float4 v = m4[(size_t)id[j] * ITEM4 + t];
        float wj = w[j];
        acc.x += wj * v.x; acc.y += wj * v.y; acc.z += wj * v.z; acc.w += wj * v.w;
    }
    ((float4*)out)[t] = acc;
}

extern "C" void kernel_launch(void* const* d_in, const int* in_sizes, int n_in,
                              void* d_out, int out_size, void* d_ws, size_t ws_size,
                              hipStream_t stream) {
    const float* q   = (const float*)d_in[0];   // [4,128,16,16]
    const float* mem = (const float*)d_in[1];   // [N,4,128,16,16]
    const int*   kp  = (const int*)d_in[2];     // scalar k
    float* out = (float*)d_out;

    const int N = in_sizes[1] / (BQ * DIM);     // 2000

    // Workspace layout:
    float2* dn   = (float2*)d_ws;               // N*BQ float2 = 64 KB
    float*  wts  = (float*)(dn + (size_t)N * BQ);
    int*    tidx = (int*)(wts + 64);

    dot_norm_kernel<<<2048, 512, 0, stream>>>(q, mem, dn, N);
    topk_softmax_kernel<<<1, 512, 0, stream>>>(q, dn, kp, wts, tidx, N);
    wsum_kernel<<<(ITEM4 + 255) / 256, 256, 0, stream>>>(mem, wts, tidx, kp, out);
}

// Round 7
// 191.876 us; speedup vs baseline: 1.4525x; 1.1320x over previous
//
#include <hip/hip_runtime.h>
#include <hip/hip_bf16.h>
#include <math.h>

// Problem constants (from reference setup): b=4, c=128, h=16, w=16
//   D    = 128*16*16 = 32768 floats per (n,b) slice
//   DIM4 = D/4 = 8192 float4 per slice; 128 KB per slice
#define BQ    4
#define DIM   32768
#define DIM4  8192
#define ITEM4 32768   // (4*32768)/4 float4 per memory item
#define EPS   1e-8f
#define QREG  16      // float4 per thread of register-resident query slice

using f4 = __attribute__((ext_vector_type(4))) float;

// ---------------- Kernel B: block-per-(n,b), full-item load window ----------------
// R6-proven structure: each 512-thread block pins one batch row b (query slice
// in registers) and grid-strides over n; whole 128 KB item in flight per block,
// one __syncthreads per item (double-buffered LDS reduce).
// NEW: memory-bank loads are NON-TEMPORAL — the stream has zero reuse (each
// slice read by exactly one block), so skipping L2/L3 fills removes pure
// cache-management overhead from the 1 GB stream.
__global__ __launch_bounds__(512) void dot_norm_kernel(
        const float* __restrict__ q, const float* __restrict__ mem,
        float2* __restrict__ dn, int N) {
    const int b    = blockIdx.x & 3;
    const int bn   = blockIdx.x >> 2;       // block index within this b
    const int nblk = gridDim.x >> 2;        // blocks per b
    const int wid  = threadIdx.x >> 6;
    const int lane = threadIdx.x & 63;

    const f4* q4 = (const f4*)(q + (size_t)b * DIM);
    f4 qr[QREG];
    #pragma unroll
    for (int j = 0; j < QREG; ++j) qr[j] = q4[threadIdx.x + j * 512];

    __shared__ float sd[2][8], sn[2][8];
    int buf = 0;

    for (int n = bn; n < N; n += nblk, buf ^= 1) {
        const f4* m4 = (const f4*)(mem + ((size_t)n * BQ + b) * DIM);
        float dot = 0.f, nrm = 0.f;
        #pragma unroll
        for (int j = 0; j < QREG; ++j) {
            f4 m = __builtin_nontemporal_load(m4 + threadIdx.x + j * 512);
            f4 a = qr[j];
            dot += a.x * m.x + a.y * m.y + a.z * m.z + a.w * m.w;
            nrm += m.x * m.x + m.y * m.y + m.z * m.z + m.w * m.w;
        }
        #pragma unroll
        for (int off = 32; off > 0; off >>= 1) {
            dot += __shfl_down(dot, off);
            nrm += __shfl_down(nrm, off);
        }
        if (lane == 0) { sd[buf][wid] = dot; sn[buf][wid] = nrm; }
        __syncthreads();
        if (threadIdx.x == 0) {
            float d = 0.f, n2 = 0.f;
            #pragma unroll
            for (int w = 0; w < 8; ++w) { d += sd[buf][w]; n2 += sn[buf][w]; }
            dn[n * BQ + b] = make_float2(d, n2);
        }
        // No trailing barrier: next iteration writes buf^1; buf is only
        // rewritten two iterations on, after an intervening barrier.
    }
}

// ---------------- Kernel C: qnorm + sims -> top-k -> softmax ----------------
// Single block, 512 threads. sims in registers (4/thread). Each of the k
// rounds costs ONE barrier: wave argmax -> swv[parity][] -> barrier -> all
// threads redundantly compute the block winner (8 compares) -> owner
// invalidates. Double-buffered swv/swi makes the 1-barrier scheme race-free.
__global__ __launch_bounds__(512) void topk_softmax_kernel(
        const float* __restrict__ q,
        const float2* __restrict__ dn,
        const int* __restrict__ kp,
        float* __restrict__ weights,
        int* __restrict__ topidx,
        int N) {
    const int k    = *kp;
    const int lane = threadIdx.x & 63;
    const int wid  = threadIdx.x >> 6;

    __shared__ float sq[8];
    __shared__ float qden[BQ];
    __shared__ float swv[2][8];
    __shared__ int   swi[2][8];
    __shared__ float tvals[64];
    __shared__ int   tidxs[64];

    // --- query norms: wave w handles (b = w&3, half = w>>2), 64 float4/lane ---
    {
        const int b = wid & 3, half = wid >> 2;
        const f4* q4 = (const f4*)(q + (size_t)b * DIM) + half * (DIM4 / 2);
        float s = 0.f;
        #pragma unroll 8
        for (int j = 0; j < 64; ++j) {
            f4 v = q4[lane + j * 64];
            s += v.x * v.x + v.y * v.y + v.z * v.z + v.w * v.w;
        }
        #pragma unroll
        for (int off = 32; off > 0; off >>= 1) s += __shfl_down(s, off);
        if (lane == 0) sq[wid] = s;
    }
    __syncthreads();
    if (threadIdx.x < BQ)
        qden[threadIdx.x] = fmaxf(sqrtf(sq[threadIdx.x] + sq[threadIdx.x + 4]), EPS);
    __syncthreads();

    // --- sims in registers: thread t owns n = t, t+512, t+1024, t+1536 ---
    float sv[4];
    #pragma unroll
    for (int i = 0; i < 4; ++i) {
        const int n = threadIdx.x + i * 512;
        if (n < N) {
            const f4* p4 = (const f4*)(dn + (size_t)n * BQ);
            f4 v0 = p4[0];  // (dot0, nrm0, dot1, nrm1)
            f4 v1 = p4[1];  // (dot2, nrm2, dot3, nrm3)
            float s = v0.x / (qden[0] * fmaxf(sqrtf(v0.y), EPS))
                    + v0.z / (qden[1] * fmaxf(sqrtf(v0.w), EPS))
                    + v1.x / (qden[2] * fmaxf(sqrtf(v1.y), EPS))
                    + v1.z / (qden[3] * fmaxf(sqrtf(v1.w), EPS));
            sv[i] = s * (1.0f / BQ);
        } else {
            sv[i] = -INFINITY;
        }
    }

    // --- iterative top-k (lowest-index tie-break, matches jax.lax.top_k) ---
    for (int it = 0; it < k; ++it) {
        const int par = it & 1;
        // local argmax over 4 regs (ascending i => lowest n wins ties)
        float best = sv[0];
        int bi = threadIdx.x;
        #pragma unroll
        for (int i = 1; i < 4; ++i) {
            if (sv[i] > best) { best = sv[i]; bi = threadIdx.x + i * 512; }
        }
        // wave argmax
        #pragma unroll
        for (int off = 32; off > 0; off >>= 1) {
            float ov = __shfl_down(best, off);
            int   oi = __shfl_down(bi, off);
            if (ov > best || (ov == best && oi < bi)) { best = ov; bi = oi; }
        }
        if (lane == 0) { swv[par][wid] = best; swi[par][wid] = bi; }
        __syncthreads();
        // all threads redundantly reduce the 8 wave winners
        float bv = swv[par][0]; int bx = swi[par][0];
        #pragma unroll
        for (int w = 1; w < 8; ++w) {
            if (swv[par][w] > bv || (swv[par][w] == bv && swi[par][w] < bx)) {
                bv = swv[par][w]; bx = swi[par][w];
            }
        }
        if (threadIdx.x == 0) { tvals[it] = bv; tidxs[it] = bx; }
        // owner invalidates its register copy
        if ((bx & 511) == (int)threadIdx.x) sv[bx >> 9] = -INFINITY;
    }

    if (threadIdx.x == 0) {
        float m = tvals[0];          // descending: first is the max
        float sum = 0.f;
        for (int i = 0; i < k; ++i) sum += expf(tvals[i] - m);
        float inv = 1.0f / sum;
        for (int i = 0; i < k; ++i) {
            weights[i] = expf(tvals[i] - m) * inv;
            topidx[i]  = tidxs[i];
        }
    }
}

// ---------------- Kernel D: weighted gather-sum of selected items ----------------
__global__ __launch_bounds__(128) void wsum_kernel(
        const float* __restrict__ mem,
        const float* __restrict__ weights,
        const int* __restrict__ topidx,
        const int* __restrict__ kp,
        float* __restrict__ out) {
    const int k = *kp;
    __shared__ float w[64];
    __shared__ int   id[64];
    if ((int)threadIdx.x < k) {
        w[threadIdx.x]  = weights[threadIdx.x];
        id[threadIdx.x] = topidx[threadIdx.x];
    }
    __syncthreads();
    const int t = blockIdx.x * blockDim.x + threadIdx.x;   // float4 index within item
    if (t >= ITEM4) return;
    const f4* m4 = (const f4*)mem;
    f4 acc = {0.f, 0.f, 0.f, 0.f};
    #pragma unroll 4
    for (int j = 0; j < k; ++j) {
        f4 v = m4[(size_t)id[j] * ITEM4 + t];
        float wj = w[j];
        acc.x += wj * v.x; acc.y += wj * v.y; acc.z += wj * v.z; acc.w += wj * v.w;
    }
    ((f4*)out)[t] = acc;
}

extern "C" void kernel_launch(void* const* d_in, const int* in_sizes, int n_in,
                              void* d_out, int out_size, void* d_ws, size_t ws_size,
                              hipStream_t stream) {
    const float* q   = (const float*)d_in[0];   // [4,128,16,16]
    const float* mem = (const float*)d_in[1];   // [N,4,128,16,16]
    const int*   kp  = (const int*)d_in[2];     // scalar k
    float* out = (float*)d_out;

    const int N = in_sizes[1] / (BQ * DIM);     // 2000

    // Workspace layout:
    float2* dn   = (float2*)d_ws;               // N*BQ float2 = 64 KB
    float*  wts  = (float*)(dn + (size_t)N * BQ);
    int*    tidx = (int*)(wts + 64);

    dot_norm_kernel<<<2048, 512, 0, stream>>>(q, mem, dn, N);
    topk_softmax_kernel<<<1, 512, 0, stream>>>(q, dn, kp, wts, tidx, N);
    wsum_kernel<<<(ITEM4 + 127) / 128, 128, 0, stream>>>(mem, wts, tidx, kp, out);
}